// Round 8
// baseline (59.965 us; speedup 1.0000x reference)
//
#include <hip/hip_runtime.h>
#include <hip/hip_fp16.h>
#include <stdint.h>

#define TOKENS 2048
#define DIM    2048
#define GROUP  128
#define NGK    16   // K-groups per row

typedef __attribute__((ext_vector_type(4)))  int   i32x4;
typedef __attribute__((ext_vector_type(16))) int   i32x16;
typedef __attribute__((ext_vector_type(4)))  float f32x4;
typedef __attribute__((ext_vector_type(16))) float f32x16;

// ---------------- quantization (int8 q/4 + per-group scale*4) ----------------

__device__ __forceinline__ float group32_sum(float v) {
#pragma unroll
  for (int off = 16; off > 0; off >>= 1)
    v += __shfl_xor(v, off, 64);
  return v;
}

// nearest merged-grid point in q/4 units: ints {-7..7} U +-{12,16,24,32,48,64,96}
__device__ __forceinline__ float nearest_q4(float u) {
  float qi = fminf(fmaxf(rintf(u), -7.f), 7.f);
  float a = fabsf(u);
  float m = a <= 14.f ? 12.f : a <= 20.f ? 16.f : a <= 28.f ? 24.f
          : a <= 40.f ? 32.f : a <= 56.f ? 48.f : a <= 80.f ? 64.f : 96.f;
  float qo = copysignf(m, u);
  return (fabsf(u - qo) < fabsf(u - qi)) ? qo : qi;   // int grid wins ties
}

__global__ __launch_bounds__(256) void quant2_kernel(
    const float* __restrict__ x, const float* __restrict__ w,
    int8_t* __restrict__ q8,          // qx (4MB) ++ qw (4MB), values = grid/4
    float* __restrict__ ssxT,         // [16][2048]  scale*4, transposed
    float* __restrict__ sswT) {       // [16][2048]
  const int wid  = threadIdx.x >> 6;
  const int lane = threadIdx.x & 63;
  const int l    = lane & 31;
  const int g    = blockIdx.x * 8 + wid * 2 + (lane >> 5);
  const int NG1  = TOKENS * DIM / GROUP;   // 32768

  const float alpha = (g < NG1) ? 0.9f : 1.0f;
  const float* src  = (g < NG1) ? x : w;
  const int grow    = (g < NG1) ? g : g - NG1;
  const size_t sbase = (size_t)grow * GROUP + l * 4;

  const float4 v = *reinterpret_cast<const float4*>(src + sbase);

  const float mean = group32_sum(v.x + v.y + v.z + v.w) * (1.0f / 128.0f);
  const float d0 = v.x - mean, d1 = v.y - mean, d2 = v.z - mean, d3 = v.w - mean;
  const float var = group32_sum(d0 * d0 + d1 * d1 + d2 * d2 + d3 * d3) *
                    (1.0f / 127.0f);
  const float scale = (fabsf(mean) + 3.0f * sqrtf(var)) * alpha / 28.0f;
  const float rs4 = 0.25f / scale;          // to q/4 units

  float q0 = nearest_q4(v.x * rs4);
  float q1 = nearest_q4(v.y * rs4);
  float q2 = nearest_q4(v.z * rs4);
  float q3 = nearest_q4(v.w * rs4);
  // victim masking: outlier (|q/4|>8) zeroes its pair partner
  if (fabsf(q0) > 8.0f)      q1 = 0.0f;
  else if (fabsf(q1) > 8.0f) q0 = 0.0f;
  if (fabsf(q2) > 8.0f)      q3 = 0.0f;
  else if (fabsf(q3) > 8.0f) q2 = 0.0f;

  const int p = ((int)q0 & 255) | (((int)q1 & 255) << 8) |
                (((int)q2 & 255) << 16) | (((int)q3 & 255) << 24);
  reinterpret_cast<int*>(q8)[(size_t)g * 32 + l] = p;

  if (l == 0) {
    const float ss = 4.0f * scale;
    if (g < NG1) ssxT[(grow & 15) * 2048 + (grow >> 4)] = ss;
    else         sswT[(grow & 15) * 2048 + (grow >> 4)] = ss;
  }
}

// ---------------- GEMM: C = sum_g ssx*ssw*(int8 group dot) ----------------
// BM=BN=128, BK=128 (one scale group). 512 thr = 8 waves (wr,wc,wz):
// wave tile 64x64 (2x2 of 32x32), wz splits the 4 K=32 slices 2+2.
// mfma_i32_32x32x32_i8, exact int accumulation per group, then per-group
// fp32 scale-apply from LDS-staged scale tables. 3-deep pipeline with
// counted vmcnt; XOR swizzle ((row&7)<<4) both-sides; XCD 8x4 chunk swizzle.
// Epilogue: 2-way LDS reduction over wz.
//
// __launch_bounds__(512, 1): LDS (112 KB) already caps at 1 block/CU =
// 2 waves/SIMD, so a 256-VGPR allocation costs no occupancy. R7's (512,2)
// capped VGPR at 128 < ~190 live -> 59 MB/dispatch scratch spills
// (WRITE_SIZE 75.7 MB vs 16 MB of C, MfmaUtil 5%).

__device__ __forceinline__ void gload_lds16(const int8_t* g, char* l) {
  __builtin_amdgcn_global_load_lds(
      (__attribute__((address_space(1))) uint32_t*)g,
      (__attribute__((address_space(3))) uint32_t*)l, 16, 0, 0);
}

__global__ __launch_bounds__(512, 1) void gemm_kernel(
    const int8_t* __restrict__ Aq, const int8_t* __restrict__ Bq,
    const float* __restrict__ ssxT, const float* __restrict__ sswT,
    float* __restrict__ C) {
  __shared__ char lds_raw[3 * 32768 + 16384];   // 96 KB stages + 16 KB scales
  float* ssx_l = (float*)(lds_raw + 98304);             // [16][128]
  float* ssw_l = (float*)(lds_raw + 98304 + 8192);      // [16][128]

  const int tid  = threadIdx.x;
  const int lane = tid & 63;
  const int wid  = tid >> 6;
  const int wz   = wid & 1;
  const int wq   = wid >> 1;
  const int wr   = wq >> 1;
  const int wc   = wq & 1;
  const int r31  = lane & 31;
  const int hi   = lane >> 5;

  const int bid = blockIdx.x;
  const int cxy = bid & 7;
  const int idx = bid >> 3;
  const int bm  = ((cxy >> 2) << 3) + (idx >> 2);
  const int bn  = ((cxy & 3) << 2) + (idx & 3);

  const int8_t* gA = Aq + (size_t)(bm * 128) * DIM;
  const int8_t* gB = Bq + (size_t)(bn * 128) * DIM;

  auto stage = [&](char* buf, int kt) {
#pragma unroll
    for (int i = 0; i < 2; ++i) {     // A: 128x128 i8 = 16 KB
      int P   = (i * 512 + tid) * 16;
      int row = P >> 7;
      int cb  = (P & 127) ^ ((row & 7) << 4);
      gload_lds16(gA + (size_t)row * DIM + kt * 128 + cb, buf + P);
    }
#pragma unroll
    for (int i = 0; i < 2; ++i) {     // B: 16 KB
      int P   = (i * 512 + tid) * 16;
      int row = P >> 7;
      int cb  = (P & 127) ^ ((row & 7) << 4);
      gload_lds16(gB + (size_t)row * DIM + kt * 128 + cb, buf + 16384 + P);
    }
  };

  f32x16 accf[2][2] = {};
  const i32x16 zacc = {};

  auto compute = [&](const char* buf, int gk) {
    const char* cA = buf;
    const char* cB = buf + 16384;
    i32x16 acci[2][2];
#pragma unroll
    for (int s = 0; s < 2; ++s) {
      const int ks = wz * 2 + s;                  // this wave's K=32 slice
      const int cb = ks * 32 + hi * 16;
      i32x4 af[2], bf[2];
#pragma unroll
      for (int mt = 0; mt < 2; ++mt) {
        int row = wr * 64 + mt * 32 + r31;
        int pc  = cb ^ ((row & 7) << 4);
        af[mt] = *reinterpret_cast<const i32x4*>(cA + (row << 7) + pc);
      }
#pragma unroll
      for (int nt = 0; nt < 2; ++nt) {
        int row = wc * 64 + nt * 32 + r31;
        int pc  = cb ^ ((row & 7) << 4);
        bf[nt] = *reinterpret_cast<const i32x4*>(cB + (row << 7) + pc);
      }
      __builtin_amdgcn_s_setprio(1);
#pragma unroll
      for (int mt = 0; mt < 2; ++mt)
#pragma unroll
        for (int nt = 0; nt < 2; ++nt)
          acci[mt][nt] = __builtin_amdgcn_mfma_i32_32x32x32_i8(
              af[mt], bf[nt], s == 0 ? zacc : acci[mt][nt], 0, 0, 0);
      __builtin_amdgcn_s_setprio(0);
    }
    // per-group scale apply: accf += ssx[row]*ssw[col]*float(acci)
    float swv[2];
#pragma unroll
    for (int nt = 0; nt < 2; ++nt)
      swv[nt] = ssw_l[gk * 128 + wc * 64 + nt * 32 + r31];
#pragma unroll
    for (int mt = 0; mt < 2; ++mt) {
      f32x4 sxv[4];
#pragma unroll
      for (int blk = 0; blk < 4; ++blk)
        sxv[blk] = *reinterpret_cast<const f32x4*>(
            &ssx_l[gk * 128 + wr * 64 + mt * 32 + 8 * blk + 4 * hi]);
#pragma unroll
      for (int nt = 0; nt < 2; ++nt)
#pragma unroll
        for (int r = 0; r < 16; ++r)
          accf[mt][nt][r] +=
              sxv[r >> 2][r & 3] * (swv[nt] * (float)acci[mt][nt][r]);
    }
  };

  char* S0 = lds_raw;
  char* S1 = lds_raw + 32768;
  char* S2 = lds_raw + 65536;

  stage(S0, 0);
  stage(S1, 1);
#pragma unroll
  for (int i = 0; i < 4; ++i) {        // stage scale tables (once)
    int id2 = i * 512 + tid;           // 0..2047
    int gk = id2 >> 7, r = id2 & 127;
    ssx_l[gk * 128 + r] = ssxT[gk * 2048 + bm * 128 + r];
    ssw_l[gk * 128 + r] = sswT[gk * 2048 + bn * 128 + r];
  }
  __syncthreads();                     // drains everything (prologue only)

  auto iter = [&](int j, char* cbuf, char* sbuf) {
    if (j < 14) {
      stage(sbuf, j + 2);
      asm volatile("s_waitcnt vmcnt(8)" ::: "memory");
    } else if (j == 14) {
      asm volatile("s_waitcnt vmcnt(4)" ::: "memory");
    } else {
      asm volatile("s_waitcnt vmcnt(0)" ::: "memory");
    }
    __builtin_amdgcn_s_barrier();
    compute(cbuf, j);
    __builtin_amdgcn_s_barrier();
  };

  for (int t = 0; t < 15; t += 3) {    // j = 0..14
    iter(t + 0, S0, S2);
    iter(t + 1, S1, S0);
    iter(t + 2, S2, S1);
  }
  iter(15, S0, S2);                    // j = 15 (no stage)

  // ---- 2-way split-K reduction over wz ----
  __syncthreads();
  float* red = (float*)lds_raw;        // 64 KB
  if (wz == 1) {
#pragma unroll
    for (int mt = 0; mt < 2; ++mt)
#pragma unroll
      for (int nt = 0; nt < 2; ++nt) {
        const int t = mt * 2 + nt;
#pragma unroll
        for (int q = 0; q < 4; ++q) {
          f32x4 v;
          v.x = accf[mt][nt][q * 4 + 0];
          v.y = accf[mt][nt][q * 4 + 1];
          v.z = accf[mt][nt][q * 4 + 2];
          v.w = accf[mt][nt][q * 4 + 3];
          *reinterpret_cast<f32x4*>(
              red + (size_t)((wq * 16 + t * 4 + q) * 64 + lane) * 4) = v;
        }
      }
  }
  __syncthreads();
  if (wz == 0) {
    const int crow0 = bm * 128 + wr * 64 + 4 * hi;
    const int ccol0 = bn * 128 + wc * 64 + r31;
#pragma unroll
    for (int mt = 0; mt < 2; ++mt)
#pragma unroll
      for (int nt = 0; nt < 2; ++nt) {
        const int t = mt * 2 + nt;
#pragma unroll
        for (int q = 0; q < 4; ++q) {
          f32x4 v = *reinterpret_cast<const f32x4*>(
              red + (size_t)((wq * 16 + t * 4 + q) * 64 + lane) * 4);
          accf[mt][nt][q * 4 + 0] += v.x;
          accf[mt][nt][q * 4 + 1] += v.y;
          accf[mt][nt][q * 4 + 2] += v.z;
          accf[mt][nt][q * 4 + 3] += v.w;
        }
#pragma unroll
        for (int r = 0; r < 16; ++r) {
          int row = crow0 + mt * 32 + (r & 3) + 8 * (r >> 2);
          int col = ccol0 + nt * 32;
          C[(size_t)row * DIM + col] = accf[mt][nt][r];
        }
      }
  }
}

// ---------------- launch ----------------

extern "C" void kernel_launch(void* const* d_in, const int* in_sizes, int n_in,
                              void* d_out, int out_size, void* d_ws,
                              size_t ws_size, hipStream_t stream) {
  const float* x = (const float*)d_in[0];
  const float* w = (const float*)d_in[1];
  float* out = (float*)d_out;

  int8_t* qx   = (int8_t*)d_ws;                         // 4 MB
  int8_t* qw   = qx + (size_t)TOKENS * DIM;             // 4 MB
  float*  ssxT = (float*)(qw + (size_t)DIM * DIM);      // 128 KB
  float*  sswT = ssxT + NGK * 2048;                     // 128 KB

  const int ngroups = 2 * TOKENS * DIM / GROUP;         // 65536
  quant2_kernel<<<ngroups / 8, 256, 0, stream>>>(x, w, qx, ssxT, sswT);

  gemm_kernel<<<256, 512, 0, stream>>>(qx, qw, ssxT, sswT, out);
}

// Round 9
// 33.937 us; speedup vs baseline: 1.7670x; 1.7670x over previous
//
#include <hip/hip_runtime.h>
#include <hip/hip_fp16.h>
#include <stdint.h>

#define TOKENS 2048
#define DIM    2048
#define GROUP  128
#define NGK    16   // K-groups per row

typedef __attribute__((ext_vector_type(4)))  int   i32x4;
typedef __attribute__((ext_vector_type(16))) int   i32x16;
typedef __attribute__((ext_vector_type(4)))  float f32x4;
typedef __attribute__((ext_vector_type(16))) float f32x16;

// ---------------- quantization (int8 q/4 + per-group scale*4) ----------------

__device__ __forceinline__ float group32_sum(float v) {
#pragma unroll
  for (int off = 16; off > 0; off >>= 1)
    v += __shfl_xor(v, off, 64);
  return v;
}

// nearest merged-grid point in q/4 units: ints {-7..7} U +-{12,16,24,32,48,64,96}
__device__ __forceinline__ float nearest_q4(float u) {
  float qi = fminf(fmaxf(rintf(u), -7.f), 7.f);
  float a = fabsf(u);
  float m = a <= 14.f ? 12.f : a <= 20.f ? 16.f : a <= 28.f ? 24.f
          : a <= 40.f ? 32.f : a <= 56.f ? 48.f : a <= 80.f ? 64.f : 96.f;
  float qo = copysignf(m, u);
  return (fabsf(u - qo) < fabsf(u - qi)) ? qo : qi;   // int grid wins ties
}

__global__ __launch_bounds__(256) void quant2_kernel(
    const float* __restrict__ x, const float* __restrict__ w,
    int8_t* __restrict__ q8,          // qx (4MB) ++ qw (4MB), values = grid/4
    float* __restrict__ ssxT,         // [16][2048]  scale*4, transposed
    float* __restrict__ sswT) {       // [16][2048]
  const int wid  = threadIdx.x >> 6;
  const int lane = threadIdx.x & 63;
  const int l    = lane & 31;
  const int g    = blockIdx.x * 8 + wid * 2 + (lane >> 5);
  const int NG1  = TOKENS * DIM / GROUP;   // 32768

  const float alpha = (g < NG1) ? 0.9f : 1.0f;
  const float* src  = (g < NG1) ? x : w;
  const int grow    = (g < NG1) ? g : g - NG1;
  const size_t sbase = (size_t)grow * GROUP + l * 4;

  const float4 v = *reinterpret_cast<const float4*>(src + sbase);

  const float mean = group32_sum(v.x + v.y + v.z + v.w) * (1.0f / 128.0f);
  const float d0 = v.x - mean, d1 = v.y - mean, d2 = v.z - mean, d3 = v.w - mean;
  const float var = group32_sum(d0 * d0 + d1 * d1 + d2 * d2 + d3 * d3) *
                    (1.0f / 127.0f);
  const float scale = (fabsf(mean) + 3.0f * sqrtf(var)) * alpha / 28.0f;
  const float rs4 = 0.25f / scale;          // to q/4 units

  float q0 = nearest_q4(v.x * rs4);
  float q1 = nearest_q4(v.y * rs4);
  float q2 = nearest_q4(v.z * rs4);
  float q3 = nearest_q4(v.w * rs4);
  // victim masking: outlier (|q/4|>8) zeroes its pair partner
  if (fabsf(q0) > 8.0f)      q1 = 0.0f;
  else if (fabsf(q1) > 8.0f) q0 = 0.0f;
  if (fabsf(q2) > 8.0f)      q3 = 0.0f;
  else if (fabsf(q3) > 8.0f) q2 = 0.0f;

  const int p = ((int)q0 & 255) | (((int)q1 & 255) << 8) |
                (((int)q2 & 255) << 16) | (((int)q3 & 255) << 24);
  reinterpret_cast<int*>(q8)[(size_t)g * 32 + l] = p;

  if (l == 0) {
    const float ss = 4.0f * scale;
    if (g < NG1) ssxT[(grow & 15) * 2048 + (grow >> 4)] = ss;
    else         sswT[(grow & 15) * 2048 + (grow >> 4)] = ss;
  }
}

// ---------------- GEMM: C = sum_g ssx*ssw*(int8 group dot) ----------------
// BM=128, BN=64, BK=128 (one scale group). 256 thr = 4 waves (wr,wc), wave
// tile 64x32 (2x1 of 32x32) -> accf[2]+acci[2] = 64 regs total accumulator:
// no spill at ANY allocator split (R7/R8 lesson: 512-thr blocks force 2
// waves/SIMD -> 128 arch VGPR cap -> 59 MB scratch with dual 64-reg accs).
// Grid 512 = 2 blocks/CU (co-resident overlap). mfma_i32_32x32x32_i8,
// exact int group dot, fp32 scale-apply from LDS tables. 2-deep pipeline,
// counted vmcnt(6); XOR swizzle ((row&7)<<4) both-sides; XCD 4x16 chunks.
// No split-K -> no reduction epilogue.

__device__ __forceinline__ void gload_lds16(const int8_t* g, char* l) {
  __builtin_amdgcn_global_load_lds(
      (__attribute__((address_space(1))) uint32_t*)g,
      (__attribute__((address_space(3))) uint32_t*)l, 16, 0, 0);
}

__global__ __launch_bounds__(256, 2) void gemm_kernel(
    const int8_t* __restrict__ Aq, const int8_t* __restrict__ Bq,
    const float* __restrict__ ssxT, const float* __restrict__ sswT,
    float* __restrict__ C) {
  // 2 stages x (A 16K + B 8K) = 48 KB, + scales 12 KB = 60 KB
  __shared__ char lds_raw[2 * 24576 + 12288];
  float* ssx_l = (float*)(lds_raw + 49152);          // [16][128]
  float* ssw_l = (float*)(lds_raw + 49152 + 8192);   // [16][64]

  const int tid  = threadIdx.x;
  const int lane = tid & 63;
  const int wid  = tid >> 6;       // 0..3
  const int wr   = wid >> 1;       // 0..1 (64 rows)
  const int wc   = wid & 1;        // 0..1 (32 cols)
  const int r31  = lane & 31;
  const int hi   = lane >> 5;

  // XCD c owns bm in [(c&3)*4,+4), bn in [(c>>2)*16,+16): ~3 MB panels -> L2
  const int bid = blockIdx.x;
  const int c   = bid & 7;
  const int idx = bid >> 3;                   // 0..63
  const int bm  = ((c & 3) << 2) + (idx >> 4);    // 0..15
  const int bn  = ((c >> 2) << 4) + (idx & 15);   // 0..31

  const int8_t* gA = Aq + (size_t)(bm * 128) * DIM;
  const int8_t* gB = Bq + (size_t)(bn * 64) * DIM;

  auto stage = [&](char* buf, int g) {
#pragma unroll
    for (int i = 0; i < 4; ++i) {     // A: 128x128 i8 = 16 KB
      int P   = (i * 256 + tid) * 16;
      int row = P >> 7;
      int cb  = (P & 127) ^ ((row & 7) << 4);
      gload_lds16(gA + (size_t)row * DIM + g * 128 + cb, buf + P);
    }
#pragma unroll
    for (int i = 0; i < 2; ++i) {     // B: 64x128 i8 = 8 KB
      int P   = (i * 256 + tid) * 16;
      int row = P >> 7;
      int cb  = (P & 127) ^ ((row & 7) << 4);
      gload_lds16(gB + (size_t)row * DIM + g * 128 + cb, buf + 16384 + P);
    }
  };

  // ---- stage scale tables, then full drain (keeps manual vmcnt exact) ----
#pragma unroll
  for (int i = 0; i < 2; ++i) {       // ssx: 2048 floats
    int f = (i * 256 + tid) * 4;      // gk = f>>7, r = f&127 (4-aligned)
    *reinterpret_cast<f32x4*>(&ssx_l[f]) =
        *reinterpret_cast<const f32x4*>(&ssxT[(f >> 7) * 2048 + bm * 128 + (f & 127)]);
  }
  {                                   // ssw: 1024 floats
    int f = tid * 4;                  // gk = f>>6, r = f&63
    *reinterpret_cast<f32x4*>(&ssw_l[f]) =
        *reinterpret_cast<const f32x4*>(&sswT[(f >> 6) * 2048 + bn * 64 + (f & 63)]);
  }
  __syncthreads();                    // drain scale loads + publish LDS

  f32x16 accf[2] = {};
  const i32x16 zacc = {};

  auto compute = [&](const char* buf, int gk) {
    const char* cA = buf;
    const char* cB = buf + 16384;
    i32x16 acci[2];
#pragma unroll
    for (int ks = 0; ks < 4; ++ks) {
      const int cb = ks * 32 + hi * 16;
      i32x4 af[2], bf;
#pragma unroll
      for (int mt = 0; mt < 2; ++mt) {
        int row = wr * 64 + mt * 32 + r31;
        int pc  = cb ^ ((row & 7) << 4);
        af[mt] = *reinterpret_cast<const i32x4*>(cA + (row << 7) + pc);
      }
      {
        int row = wc * 32 + r31;
        int pc  = cb ^ ((row & 7) << 4);
        bf = *reinterpret_cast<const i32x4*>(cB + (row << 7) + pc);
      }
      __builtin_amdgcn_s_setprio(1);
#pragma unroll
      for (int mt = 0; mt < 2; ++mt)
        acci[mt] = __builtin_amdgcn_mfma_i32_32x32x32_i8(
            af[mt], bf, ks == 0 ? zacc : acci[mt], 0, 0, 0);
      __builtin_amdgcn_s_setprio(0);
    }
    // accf += ssx[row] * ssw[col] * float(acci)
    const float sw = ssw_l[gk * 64 + wc * 32 + r31];
#pragma unroll
    for (int mt = 0; mt < 2; ++mt)
#pragma unroll
      for (int q = 0; q < 4; ++q) {
        f32x4 sx = *reinterpret_cast<const f32x4*>(
            &ssx_l[gk * 128 + wr * 64 + mt * 32 + 8 * q + 4 * hi]);
#pragma unroll
        for (int e = 0; e < 4; ++e)
          accf[mt][q * 4 + e] += sx[e] * (sw * (float)acci[mt][q * 4 + e]);
      }
  };

  char* S0 = lds_raw;
  char* S1 = lds_raw + 24576;

  stage(S0, 0);
#pragma unroll 2
  for (int j = 0; j < NGK; ++j) {     // 16 K-groups
    if (j + 1 < NGK) {
      stage((j & 1) ? S0 : S1, j + 1);
      asm volatile("s_waitcnt vmcnt(6)" ::: "memory");   // j's 6 loads done
    } else {
      asm volatile("s_waitcnt vmcnt(0)" ::: "memory");
    }
    __builtin_amdgcn_s_barrier();
    compute((j & 1) ? S1 : S0, j);
    __builtin_amdgcn_s_barrier();
  }

  // ---- direct C write (no split-K) ----
  const int crow0 = bm * 128 + wr * 64 + 4 * hi;
  const int ccol  = bn * 64 + wc * 32 + r31;
#pragma unroll
  for (int mt = 0; mt < 2; ++mt)
#pragma unroll
    for (int r = 0; r < 16; ++r) {
      int row = crow0 + mt * 32 + (r & 3) + 8 * (r >> 2);
      C[(size_t)row * DIM + ccol] = accf[mt][r];
    }
}

// ---------------- launch ----------------

extern "C" void kernel_launch(void* const* d_in, const int* in_sizes, int n_in,
                              void* d_out, int out_size, void* d_ws,
                              size_t ws_size, hipStream_t stream) {
  const float* x = (const float*)d_in[0];
  const float* w = (const float*)d_in[1];
  float* out = (float*)d_out;

  int8_t* qx   = (int8_t*)d_ws;                         // 4 MB
  int8_t* qw   = qx + (size_t)TOKENS * DIM;             // 4 MB
  float*  ssxT = (float*)(qw + (size_t)DIM * DIM);      // 128 KB
  float*  sswT = ssxT + NGK * 2048;                     // 128 KB

  const int ngroups = 2 * TOKENS * DIM / GROUP;         // 65536
  quant2_kernel<<<ngroups / 8, 256, 0, stream>>>(x, w, qx, ssxT, sswT);

  gemm_kernel<<<512, 256, 0, stream>>>(qx, qw, ssxT, sswT, out);
}